// Round 5
// baseline (579.855 us; speedup 1.0000x reference)
//
#include <hip/hip_runtime.h>
#include <math.h>

// Batched 10-qubit statevector sim: one wave per batch element.
// State = 1024 complex amps = 16 float2 (re,im) per lane in registers.
// Amp index a = (lane << 4) | r. Wire w acts on bit 9-w of a:
//   bit<4  -> in-register 2x2, bit>=4 -> cross-lane (mask 1<<(bit-4)):
//     mask 32/16 : permlane{32,16}_swap PAIR trick (in-place half exchange)
//     mask 8     : DPP row_ror:8 ; mask 1,2 : DPP quad_perm
//     mask 4     : ds_swizzle (kept on the otherwise-idle DS pipe)
// Round-5 changes (theory: ~9.2k VALU slots/wave measured vs ~4k packed ideal):
//  (a) ALL gate math forced to v_pk_mul_f32/v_pk_fma_f32 via inline asm
//      (neg_lo/neg_hi for subtraction, op_sel for the RX re/im cross-mul).
//  (b) __launch_bounds__(256,4): 128-VGPR budget, stops AGPR bouncing that
//      VGPR_Count=28 (< 32 live state floats!) implied.
//  (c) permlane pair trick operates on whole v2f pairs -> no repack movs.

typedef float v2f __attribute__((ext_vector_type(2)));
typedef unsigned int u32;

constexpr int NQ = 10;
constexpr int NDEPTH = 6;
constexpr int NCLS = 16;

__device__ __forceinline__ float i2f(int i) { return __builtin_bit_cast(float, i); }
__device__ __forceinline__ int   f2i(float f) { return __builtin_bit_cast(int, f); }
__device__ __forceinline__ u32   f2u(float f) { return __builtin_bit_cast(u32, f); }
__device__ __forceinline__ float u2f(u32 u)   { return __builtin_bit_cast(float, u); }

// ---------------- forced packed-f32 VALU ops (VOP3P) ----------------
__device__ __forceinline__ v2f pk_mul(v2f a, v2f b) {
    v2f d; asm("v_pk_mul_f32 %0, %1, %2" : "=v"(d) : "v"(a), "v"(b)); return d;
}
__device__ __forceinline__ v2f pk_fma(v2f a, v2f b, v2f c) {   // a*b + c
    v2f d; asm("v_pk_fma_f32 %0, %1, %2, %3" : "=v"(d) : "v"(a), "v"(b), "v"(c)); return d;
}
__device__ __forceinline__ v2f pk_fnma(v2f a, v2f b, v2f c) {  // -(a*b) + c
    v2f d; asm("v_pk_fma_f32 %0, %1, %2, %3 neg_lo:[1,0,0] neg_hi:[1,0,0]"
               : "=v"(d) : "v"(a), "v"(b), "v"(c)); return d;
}
__device__ __forceinline__ v2f pk_mul_x(v2f a, v2f b) {        // {a.x*b.y, a.y*b.x}
    v2f d; asm("v_pk_mul_f32 %0, %1, %2 op_sel:[0,1] op_sel_hi:[1,0]"
               : "=v"(d) : "v"(a), "v"(b)); return d;
}

// ---- in-place half-exchange of two v2f state regs (component-wise) ----
template<int M>
__device__ __forceinline__ void plswap2(v2f& a, v2f& b) {
    if constexpr (M == 32) {
        auto p0 = __builtin_amdgcn_permlane32_swap(f2u(a.x), f2u(b.x), false, false);
        auto p1 = __builtin_amdgcn_permlane32_swap(f2u(a.y), f2u(b.y), false, false);
        a = (v2f){u2f(p0[0]), u2f(p1[0])};
        b = (v2f){u2f(p0[1]), u2f(p1[1])};
    } else {
        auto p0 = __builtin_amdgcn_permlane16_swap(f2u(a.x), f2u(b.x), false, false);
        auto p1 = __builtin_amdgcn_permlane16_swap(f2u(a.y), f2u(b.y), false, false);
        a = (v2f){u2f(p0[0]), u2f(p1[0])};
        b = (v2f){u2f(p0[1]), u2f(p1[1])};
    }
}

// ---- RY pair gate via swap trick (M = 16 or 32); validated round 4 ----
template<int M>
__device__ __forceinline__ void cross_ry_pair(v2f& va, v2f& vb, v2f c2, v2f s2) {
    plswap2<M>(va, vb);                       // va = bit0 rows (A), vb = bit1 rows (B)
    v2f C = pk_fnma(s2, vb, pk_mul(c2, va));  // c*A - s*B
    v2f D = pk_fma (s2, va, pk_mul(c2, vb));  // s*A + c*B
    plswap2<M>(C, D);                         // un-interleave
    va = C; vb = D;
}

// ---- RX pair gate: C = c*A + {s*B.im, -s*B.re}, co2 = {s,-s} ----
template<int M>
__device__ __forceinline__ void cross_rx_pair(v2f& va, v2f& vb, v2f c2, v2f co2) {
    plswap2<M>(va, vb);
    v2f C = pk_fma(c2, va, pk_mul_x(co2, vb));
    v2f D = pk_fma(c2, vb, pk_mul_x(co2, va));
    plswap2<M>(C, D);
    va = C; vb = D;
}

// ---- partner fetch for masks 1,2,4,8 ----
template<int MASK>
__device__ __forceinline__ float xp(float v, int lane) {
    if constexpr (MASK == 1) {                     // quad_perm [1,0,3,2]
        int i = f2i(v);
        return i2f(__builtin_amdgcn_update_dpp(i, i, 0xB1, 0xF, 0xF, false));
    } else if constexpr (MASK == 2) {              // quad_perm [2,3,0,1]
        int i = f2i(v);
        return i2f(__builtin_amdgcn_update_dpp(i, i, 0x4E, 0xF, 0xF, false));
    } else if constexpr (MASK == 8) {              // row_ror:8 == xor 8 in 16-row
        int i = f2i(v);
        return i2f(__builtin_amdgcn_update_dpp(i, i, 0x128, 0xF, 0xF, false));
    } else if constexpr (MASK == 4) {              // DS pipe
        return __shfl_xor(v, 4, 64);
    } else if constexpr (MASK == 16) {
        u32 u = f2u(v);
        auto pr = __builtin_amdgcn_permlane16_swap(u, u, false, false);
        return u2f((lane & 16) ? pr[0] : pr[1]);
    } else {  // MASK == 32
        u32 u = f2u(v);
        auto pr = __builtin_amdgcn_permlane32_swap(u, u, false, false);
        return u2f((lane & 32) ? pr[0] : pr[1]);
    }
}

template<int MASK>
__device__ __forceinline__ void cross_ry(v2f (&st)[16], v2f c2, v2f t2, int lane) {
#pragma unroll
    for (int r = 0; r < 16; ++r) {
        v2f p;
        p.x = xp<MASK>(st[r].x, lane);
        p.y = xp<MASK>(st[r].y, lane);
        st[r] = pk_fma(t2, p, pk_mul(c2, st[r]));
    }
}

template<int MASK>
__device__ __forceinline__ void cross_rx(v2f (&st)[16], v2f c2, v2f co2, int lane) {
#pragma unroll
    for (int r = 0; r < 16; ++r) {
        v2f p;
        p.x = xp<MASK>(st[r].y, lane);             // partner im
        p.y = xp<MASK>(st[r].x, lane);             // partner re
        st[r] = pk_fma(c2, st[r], pk_mul(co2, p)); // co2 = {s,-s}
    }
}

template<int B>
__device__ __forceinline__ void local_ry(v2f (&st)[16], v2f c2, v2f s2) {
#pragma unroll
    for (int r0 = 0; r0 < 16; ++r0) {
        if ((r0 & (1 << B)) == 0) {
            const int r1 = r0 | (1 << B);
            const v2f a0 = st[r0], a1 = st[r1];
            st[r0] = pk_fnma(s2, a1, pk_mul(c2, a0));
            st[r1] = pk_fma (s2, a0, pk_mul(c2, a1));
        }
    }
}

template<int B>
__device__ __forceinline__ void local_rx(v2f (&st)[16], v2f c2, v2f co2) {
#pragma unroll
    for (int r0 = 0; r0 < 16; ++r0) {
        if ((r0 & (1 << B)) == 0) {
            const int r1 = r0 | (1 << B);
            const v2f a0 = st[r0], a1 = st[r1];
            st[r0] = pk_fma(c2, a0, pk_mul_x(co2, a1));
            st[r1] = pk_fma(c2, a1, pk_mul_x(co2, a0));
        }
    }
}

template<int W>
__device__ __forceinline__ void apply_rx(v2f (&st)[16], float c, float s, int lane) {
    constexpr int B = 9 - W;
    const v2f c2 = {c, c}, co2 = {s, -s};
    if constexpr (B == 9) {
#pragma unroll
        for (int r = 0; r < 16; r += 2) cross_rx_pair<32>(st[r], st[r+1], c2, co2);
    } else if constexpr (B == 8) {
#pragma unroll
        for (int r = 0; r < 16; r += 2) cross_rx_pair<16>(st[r], st[r+1], c2, co2);
    } else if constexpr (B >= 4) {
        cross_rx<(1 << (B - 4))>(st, c2, co2, lane);
    } else {
        local_rx<B>(st, c2, co2);
    }
}

template<int W>
__device__ __forceinline__ void apply_ry(v2f (&st)[16], float c, float s, int lane) {
    constexpr int B = 9 - W;
    const v2f c2 = {c, c}, s2 = {s, s};
    if constexpr (B == 9) {
#pragma unroll
        for (int r = 0; r < 16; r += 2) cross_ry_pair<32>(st[r], st[r+1], c2, s2);
    } else if constexpr (B == 8) {
#pragma unroll
        for (int r = 0; r < 16; r += 2) cross_ry_pair<16>(st[r], st[r+1], c2, s2);
    } else if constexpr (B >= 4) {
        const float t = (lane & (1 << (B - 4))) ? s : -s;
        const v2f t2 = {t, t};
        cross_ry<(1 << (B - 4))>(st, c2, t2, lane);
    } else {
        local_ry<B>(st, c2, s2);
    }
}

__device__ __forceinline__ float rdlane(float v, int l) {
    return i2f(__builtin_amdgcn_readlane(f2i(v), l));   // SALU broadcast
}

__device__ __forceinline__ float wave_sum(float v, int lane) {
    v += xp<1>(v, lane);
    v += xp<2>(v, lane);
    v += xp<4>(v, lane);
    v += xp<8>(v, lane);
    v += xp<16>(v, lane);
    v += xp<32>(v, lane);
    return v;
}

__global__ void __launch_bounds__(256, 4) qnn_kernel(
    const float* __restrict__ x,       // (B, 10)
    const float* __restrict__ params,  // (6, 10)
    const float* __restrict__ w_cls,   // (16, 10)
    const float* __restrict__ b_cls,   // (16,)
    float* __restrict__ out,           // (B, 16)
    int batch)
{
    const int lane = threadIdx.x & 63;
    const int wid  = threadIdx.x >> 6;
    const int b    = blockIdx.x * (blockDim.x >> 6) + wid;
    if (b >= batch) return;

    v2f st[16];
#pragma unroll
    for (int r = 0; r < 16; ++r) st[r] = (v2f){0.f, 0.f};
    if (lane == 0) st[0].x = 1.f;      // |0...0>

    // ---- RX encoding: lane l (<10) owns angle l; broadcast via v_readlane ----
    float cx, sx;
    {
        const int l = (lane < NQ) ? lane : 0;
        __sincosf(x[b * NQ + l] * 0.5f, &sx, &cx);
    }
#define RX_W(W) apply_rx<W>(st, rdlane(cx, (W)), rdlane(sx, (W)), lane)
    RX_W(0); RX_W(1); RX_W(2); RX_W(3); RX_W(4);
    RX_W(5); RX_W(6); RX_W(7); RX_W(8); RX_W(9);
#undef RX_W

    // ---- RY params: lane l (<60) owns params[l] ----
    float cp, sp;
    {
        const int l = (lane < NDEPTH * NQ) ? lane : 0;
        __sincosf(params[l] * 0.5f, &sp, &cp);
    }

    // ---- fused CZ-chain sign (validated round 1); 4 premade packed splats ----
    const int lpar = __popc(lane & (lane >> 1) & 0x1F) & 1;
    const float ls  = lpar ? -1.f : 1.f;
    const float lsb = (lane & 1) ? -ls : ls;
    const v2f ls2   = { ls,  ls}, nls2  = {-ls, -ls};
    const v2f lsb2  = {lsb, lsb}, nlsb2 = {-lsb, -lsb};

#pragma unroll
    for (int d = 0; d < NDEPTH; ++d) {
        const int base = d * NQ;
#define RY_W(W) apply_ry<W>(st, rdlane(cp, base + (W)), rdlane(sp, base + (W)), lane)
        RY_W(0); RY_W(1); RY_W(2); RY_W(3); RY_W(4);
        RY_W(5); RY_W(6); RY_W(7); RY_W(8); RY_W(9);
#undef RY_W
#pragma unroll
        for (int r = 0; r < 16; ++r) {
            const int cr = __popc(r & (r >> 1) & 7) & 1;   // compile-time per r
            const v2f f2 = (r & 8) ? (cr ? nlsb2 : lsb2) : (cr ? nls2 : ls2);
            st[r] = pk_mul(f2, st[r]);
        }
    }

    // ---- probabilities & Z expectations ----
    float pt = 0.f, e6 = 0.f, e7 = 0.f, e8 = 0.f, e9 = 0.f;
#pragma unroll
    for (int r = 0; r < 16; ++r) {
        const float pp = fmaf(st[r].x, st[r].x, st[r].y * st[r].y);
        pt += pp;
        e9 += (r & 1) ? -pp : pp;
        e8 += (r & 2) ? -pp : pp;
        e7 += (r & 4) ? -pp : pp;
        e6 += (r & 8) ? -pp : pp;
    }

    float e[NQ];
#pragma unroll
    for (int q = 0; q < 6; ++q)                    // wires 0..5 -> lane bit (5-q)
        e[q] = ((lane >> (5 - q)) & 1) ? -pt : pt;
    e[6] = e6; e[7] = e7; e[8] = e8; e[9] = e9;

#pragma unroll
    for (int q = 0; q < NQ; ++q) e[q] = wave_sum(e[q], lane);

    // ---- linear head: lane k (<16) emits class k ----
    if (lane < NCLS) {
        float acc = b_cls[lane];
#pragma unroll
        for (int q = 0; q < NQ; ++q) acc = fmaf(e[q], w_cls[lane * NQ + q], acc);
        out[b * NCLS + lane] = acc;
    }
}

extern "C" void kernel_launch(void* const* d_in, const int* in_sizes, int n_in,
                              void* d_out, int out_size, void* d_ws, size_t ws_size,
                              hipStream_t stream) {
    const float* x      = (const float*)d_in[0];
    const float* params = (const float*)d_in[1];
    const float* w_cls  = (const float*)d_in[2];
    const float* b_cls  = (const float*)d_in[3];
    float* out = (float*)d_out;

    const int batch = in_sizes[0] / NQ;            // 65536
    const int WAVES_PER_BLOCK = 4;                 // 256 threads
    dim3 block(64 * WAVES_PER_BLOCK);
    dim3 grid((batch + WAVES_PER_BLOCK - 1) / WAVES_PER_BLOCK);
    hipLaunchKernelGGL(qnn_kernel, grid, block, 0, stream, x, params, w_cls, b_cls, out, batch);
}

// Round 6
// 391.190 us; speedup vs baseline: 1.4823x; 1.4823x over previous
//
#include <hip/hip_runtime.h>
#include <math.h>

// Batched 10-qubit statevector sim: one wave per batch element.
// State = 1024 complex amps = 16 float2 (re,im) per lane in registers.
// Amp index a = (lane << 4) | r. Wire w acts on bit 9-w of a:
//   bit<4  -> in-register 2x2, bit>=4 -> cross-lane (mask 1<<(bit-4)):
//     mask 32/16 : permlane{32,16}_swap PAIR trick (in-place half exchange)
//     mask 8     : DPP row_ror:8 ; mask 1,2 : DPP quad_perm
//     mask 4     : ds_swizzle (kept on the otherwise-idle DS pipe)
// Round-6 (algebraic FLOP cuts; packing can't help on CDNA4 since v_pk_* is
// 2 passes — 157.3TF peak == scalar fma rate):
//  (a) RX encoding layers ELIMINATED: state after encoding is the product
//      state ⊗[c_q, -i s_q] = (-i)^popcount(b) * (real product) — built
//      directly in ~60 ops (F = lane-bit factor product, 4+4+16 tensor muls,
//      4 per-lane phase vectors).
//  (b) RY gates as tan-shear: RY = c*[[1,-t],[t,1]]; apply shear only
//      (1 FMA/float instead of mul+fma), accumulate wave-uniform C = prod c,
//      scale the 10 expectations by C^2 at the end (linear in probs).
//  (c) Reverted round-5 inline-asm pk ops + launch_bounds (regressed).

typedef float v2f __attribute__((ext_vector_type(2)));
typedef unsigned int u32;

constexpr int NQ = 10;
constexpr int NDEPTH = 6;
constexpr int NCLS = 16;

__device__ __forceinline__ float i2f(int i) { return __builtin_bit_cast(float, i); }
__device__ __forceinline__ int   f2i(float f) { return __builtin_bit_cast(int, f); }
__device__ __forceinline__ u32   f2u(float f) { return __builtin_bit_cast(u32, f); }
__device__ __forceinline__ float u2f(u32 u)   { return __builtin_bit_cast(float, u); }

// ---- in-place half-exchange of two v2f state regs (component-wise) ----
template<int M>
__device__ __forceinline__ void plswap2(v2f& a, v2f& b) {
    if constexpr (M == 32) {
        auto p0 = __builtin_amdgcn_permlane32_swap(f2u(a.x), f2u(b.x), false, false);
        auto p1 = __builtin_amdgcn_permlane32_swap(f2u(a.y), f2u(b.y), false, false);
        a = (v2f){u2f(p0[0]), u2f(p1[0])};
        b = (v2f){u2f(p0[1]), u2f(p1[1])};
    } else {
        auto p0 = __builtin_amdgcn_permlane16_swap(f2u(a.x), f2u(b.x), false, false);
        auto p1 = __builtin_amdgcn_permlane16_swap(f2u(a.y), f2u(b.y), false, false);
        a = (v2f){u2f(p0[0]), u2f(p1[0])};
        b = (v2f){u2f(p0[1]), u2f(p1[1])};
    }
}

// ---- partner fetch for masks 1,2,4,8,16,32 ----
template<int MASK>
__device__ __forceinline__ float xp(float v, int lane) {
    if constexpr (MASK == 1) {                     // quad_perm [1,0,3,2]
        int i = f2i(v);
        return i2f(__builtin_amdgcn_update_dpp(i, i, 0xB1, 0xF, 0xF, false));
    } else if constexpr (MASK == 2) {              // quad_perm [2,3,0,1]
        int i = f2i(v);
        return i2f(__builtin_amdgcn_update_dpp(i, i, 0x4E, 0xF, 0xF, false));
    } else if constexpr (MASK == 8) {              // row_ror:8 == xor 8 in 16-row
        int i = f2i(v);
        return i2f(__builtin_amdgcn_update_dpp(i, i, 0x128, 0xF, 0xF, false));
    } else if constexpr (MASK == 4) {              // DS pipe
        return __shfl_xor(v, 4, 64);
    } else if constexpr (MASK == 16) {
        u32 u = f2u(v);
        auto pr = __builtin_amdgcn_permlane16_swap(u, u, false, false);
        return u2f((lane & 16) ? pr[0] : pr[1]);
    } else {  // MASK == 32
        u32 u = f2u(v);
        auto pr = __builtin_amdgcn_permlane32_swap(u, u, false, false);
        return u2f((lane & 32) ? pr[0] : pr[1]);
    }
}

// ---- RY shear pair gate via permlane swap trick (M = 16 or 32) ----
// After swap: va = bit0 rows (A), vb = bit1 rows (B), row-aligned.
// C = A - t*B ; D = t*A + B ; swap back un-interleaves.
template<int M>
__device__ __forceinline__ void cross_ry_pair(v2f& va, v2f& vb, float t) {
    plswap2<M>(va, vb);
    v2f C = va - t * vb;
    v2f D = t * va + vb;
    plswap2<M>(C, D);
    va = C; vb = D;
}

// ---- RY shear cross gate (DPP / ds masks): new = mine + ts*partner,
//      ts = +t if lane-bit set else -t ----
template<int MASK>
__device__ __forceinline__ void cross_ry(v2f (&st)[16], float ts, int lane) {
#pragma unroll
    for (int r = 0; r < 16; ++r) {
        v2f p;
        p.x = xp<MASK>(st[r].x, lane);
        p.y = xp<MASK>(st[r].y, lane);
        st[r] = st[r] + ts * p;
    }
}

// ---- RY shear local gate ----
template<int B>
__device__ __forceinline__ void local_ry(v2f (&st)[16], float t) {
#pragma unroll
    for (int r0 = 0; r0 < 16; ++r0) {
        if ((r0 & (1 << B)) == 0) {
            const int r1 = r0 | (1 << B);
            const v2f a0 = st[r0], a1 = st[r1];
            st[r0] = a0 - t * a1;
            st[r1] = t * a0 + a1;
        }
    }
}

template<int W>
__device__ __forceinline__ void apply_ry(v2f (&st)[16], float t, int lane) {
    constexpr int B = 9 - W;
    if constexpr (B == 9) {
#pragma unroll
        for (int r = 0; r < 16; r += 2) cross_ry_pair<32>(st[r], st[r+1], t);
    } else if constexpr (B == 8) {
#pragma unroll
        for (int r = 0; r < 16; r += 2) cross_ry_pair<16>(st[r], st[r+1], t);
    } else if constexpr (B >= 4) {
        constexpr int MASK = 1 << (B - 4);
        const float ts = (lane & MASK) ? t : -t;
        cross_ry<MASK>(st, ts, lane);
    } else {
        local_ry<B>(st, t);
    }
}

__device__ __forceinline__ float rdlane(float v, int l) {
    return i2f(__builtin_amdgcn_readlane(f2i(v), l));   // SALU broadcast
}

__device__ __forceinline__ float wave_sum(float v, int lane) {
    v += xp<1>(v, lane);
    v += xp<2>(v, lane);
    v += xp<4>(v, lane);
    v += xp<8>(v, lane);
    v += xp<16>(v, lane);
    v += xp<32>(v, lane);
    return v;
}

__device__ __forceinline__ float wave_prod(float v, int lane) {
    v *= xp<1>(v, lane);
    v *= xp<2>(v, lane);
    v *= xp<4>(v, lane);
    v *= xp<8>(v, lane);
    v *= xp<16>(v, lane);
    v *= xp<32>(v, lane);
    return v;
}

__global__ void __launch_bounds__(256) qnn_kernel(
    const float* __restrict__ x,       // (B, 10)
    const float* __restrict__ params,  // (6, 10)
    const float* __restrict__ w_cls,   // (16, 10)
    const float* __restrict__ b_cls,   // (16,)
    float* __restrict__ out,           // (B, 16)
    int batch)
{
    const int lane = threadIdx.x & 63;
    const int wid  = threadIdx.x >> 6;
    const int b    = blockIdx.x * (blockDim.x >> 6) + wid;
    if (b >= batch) return;

    // ---- encoding angles: lane l (<10) owns x[b,l] ----
    float cx, sx;
    {
        const int l = (lane < NQ) ? lane : 0;
        __sincosf(x[b * NQ + l] * 0.5f, &sx, &cx);
    }

    // ---- build product state directly: amp(a) = (-i)^popcount(a) * F * R ----
    // lane bits = wires 0..5 (bit 5-q), r bits = wires 6..9 (bit 9-q).
    float F = 1.f;
#pragma unroll
    for (int q = 0; q < 6; ++q) {
        const float cq = rdlane(cx, q), sq = rdlane(sx, q);
        F *= ((lane >> (5 - q)) & 1) ? sq : cq;
    }
    const float c6 = rdlane(cx, 6), s6 = rdlane(sx, 6);
    const float c7 = rdlane(cx, 7), s7 = rdlane(sx, 7);
    const float c8 = rdlane(cx, 8), s8 = rdlane(sx, 8);
    const float c9 = rdlane(cx, 9), s9 = rdlane(sx, 9);
    float m[4], n2[4];
    m[0] = c8 * c9; m[1] = c8 * s9; m[2] = s8 * c9; m[3] = s8 * s9;
    n2[0] = F * (c6 * c7); n2[1] = F * (c6 * s7);
    n2[2] = F * (s6 * c7); n2[3] = F * (s6 * s7);

    // per-lane phase (-i)^kl as v2f; variants rotated by (-i)^m for m=0..3
    const int kl = __popc(lane) & 3;
    const float pa = (kl == 0) ? 1.f : ((kl == 2) ? -1.f : 0.f);
    const float pb = (kl == 1) ? -1.f : ((kl == 3) ? 1.f : 0.f);
    v2f ph[4];
    ph[0] = (v2f){ pa,  pb};
    ph[1] = (v2f){ pb, -pa};     // ph0 * (-i)
    ph[2] = (v2f){-pa, -pb};     // ph0 * (-1)
    ph[3] = (v2f){-pb,  pa};     // ph0 * (+i)

    v2f st[16];
#pragma unroll
    for (int r = 0; r < 16; ++r) {
        const float Ar = n2[r >> 2] * m[r & 3];
        const int kr = __popc(r) & 3;              // compile-time per r
        st[r] = Ar * ph[kr];
    }

    // ---- RY params: lane l (<60) owns params[l]; shear coeff t = tan(p/2) ----
    float cp, sp;
    {
        const int l = (lane < NDEPTH * NQ) ? lane : 0;
        __sincosf(params[l] * 0.5f, &sp, &cp);
    }
    const float tp = sp / cp;                       // per-lane tan
    // wave-uniform deferred-cosine product C = prod over the 60 gates
    const float cpv = (lane < NDEPTH * NQ) ? cp : 1.f;
    const float Cprod = wave_prod(cpv, lane);
    const float C2 = Cprod * Cprod;

    // ---- fused CZ-chain sign (validated round 1) ----
    const int lpar = __popc(lane & (lane >> 1) & 0x1F) & 1;
    const float ls  = lpar ? -1.f : 1.f;
    const float lsb = (lane & 1) ? -ls : ls;

#pragma unroll
    for (int d = 0; d < NDEPTH; ++d) {
        const int base = d * NQ;
#define RY_W(W) apply_ry<W>(st, rdlane(tp, base + (W)), lane)
        RY_W(0); RY_W(1); RY_W(2); RY_W(3); RY_W(4);
        RY_W(5); RY_W(6); RY_W(7); RY_W(8); RY_W(9);
#undef RY_W
#pragma unroll
        for (int r = 0; r < 16; ++r) {
            const int cr = __popc(r & (r >> 1) & 7) & 1;   // compile-time per r
            float f = (r & 8) ? lsb : ls;
            if (cr) f = -f;
            st[r] = st[r] * f;
        }
    }

    // ---- probabilities & Z expectations (unnormalized; scaled by C2 below) ----
    float pt = 0.f, e6 = 0.f, e7 = 0.f, e8 = 0.f, e9 = 0.f;
#pragma unroll
    for (int r = 0; r < 16; ++r) {
        const float pp = fmaf(st[r].x, st[r].x, st[r].y * st[r].y);
        pt += pp;
        e9 += (r & 1) ? -pp : pp;
        e8 += (r & 2) ? -pp : pp;
        e7 += (r & 4) ? -pp : pp;
        e6 += (r & 8) ? -pp : pp;
    }

    float e[NQ];
#pragma unroll
    for (int q = 0; q < 6; ++q)                    // wires 0..5 -> lane bit (5-q)
        e[q] = ((lane >> (5 - q)) & 1) ? -pt : pt;
    e[6] = e6; e[7] = e7; e[8] = e8; e[9] = e9;

#pragma unroll
    for (int q = 0; q < NQ; ++q) e[q] = wave_sum(e[q], lane) * C2;

    // ---- linear head: lane k (<16) emits class k ----
    if (lane < NCLS) {
        float acc = b_cls[lane];
#pragma unroll
        for (int q = 0; q < NQ; ++q) acc = fmaf(e[q], w_cls[lane * NQ + q], acc);
        out[b * NCLS + lane] = acc;
    }
}

extern "C" void kernel_launch(void* const* d_in, const int* in_sizes, int n_in,
                              void* d_out, int out_size, void* d_ws, size_t ws_size,
                              hipStream_t stream) {
    const float* x      = (const float*)d_in[0];
    const float* params = (const float*)d_in[1];
    const float* w_cls  = (const float*)d_in[2];
    const float* b_cls  = (const float*)d_in[3];
    float* out = (float*)d_out;

    const int batch = in_sizes[0] / NQ;            // 65536
    const int WAVES_PER_BLOCK = 4;                 // 256 threads
    dim3 block(64 * WAVES_PER_BLOCK);
    dim3 grid((batch + WAVES_PER_BLOCK - 1) / WAVES_PER_BLOCK);
    hipLaunchKernelGGL(qnn_kernel, grid, block, 0, stream, x, params, w_cls, b_cls, out, batch);
}

// Round 7
// 322.786 us; speedup vs baseline: 1.7964x; 1.2119x over previous
//
#include <hip/hip_runtime.h>
#include <math.h>

// Batched 10-qubit statevector sim: one wave per batch element.
// State = 1024 complex amps = 16 (sr,si) float pairs per lane.
// Amp index a = (lane << 4) | r. Wire w acts on amp bit 9-w:
//   bit>=4 (lane bit b-4): wire0 permlane32-pair, wire1 permlane16-pair,
//     wire2 fmac+DPP row_ror:8, wire3 shfl_xor(4) on DS pipe,
//     wire4 fmac+DPP quad[2,3,0,1], wire5 fmac+DPP quad[1,0,3,2]
//   bit<4: in-register local shear.
// Round-7 changes (all algebraic / instruction-count cuts; VALU-bound @97%):
//  (a) v_fmac_f32 with DPP on src0: partner-fetch + FMA in ONE VALU op for
//      wires 2/4/5 (inline asm; s_nop 1 guards the VALU->DPP hazard, in-block
//      reuse distance >=16 instrs).
//  (b) CZ layers absorbed: circuit == R6 R5' R4 R3' R2 R1' C  where X' has
//      t sign-modulated by the wire's neighbor bits (per-lane +-1 precomputed,
//      per-r signs compile-time); the single C folds into the encoding; the
//      final CZ vanishes (probs ignore signs). Kills all 6 sign passes.
//  (c) Epilogue: one 6-stage WHT butterfly gives all 6 lane-wire expvals;
//      shared in-register tree for the 4 reg-wire expvals.
// RY gates stay tan-shear with deferred global cos-product C2 (round 6).

typedef unsigned int u32;

constexpr int NQ = 10;
constexpr int NCLS = 16;

__device__ __forceinline__ float i2f(int i) { return __builtin_bit_cast(float, i); }
__device__ __forceinline__ int   f2i(float f) { return __builtin_bit_cast(int, f); }
__device__ __forceinline__ u32   f2u(float f) { return __builtin_bit_cast(u32, f); }
__device__ __forceinline__ float u2f(u32 u)   { return __builtin_bit_cast(float, u); }

__device__ __forceinline__ float rdlane(float v, int l) {
    return i2f(__builtin_amdgcn_readlane(f2i(v), l));   // SALU broadcast
}

// ---- fused shear for DPP-able masks: st[k] += C * DPP(st[k]), 16 regs/block.
// s_nop 1 provides the 2 wait states required between any preceding VALU write
// and the first DPP read; within the block each reg's DPP read is its own write
// only (distinct regs per line), and cross-block reuse distance is >=16.
#define DPP16_LO(CTRL, C, sr, si) \
  asm("s_nop 1\n\t" \
      "v_fmac_f32 %0, %0, %16 "  CTRL "\n\t" \
      "v_fmac_f32 %1, %1, %16 "  CTRL "\n\t" \
      "v_fmac_f32 %2, %2, %16 "  CTRL "\n\t" \
      "v_fmac_f32 %3, %3, %16 "  CTRL "\n\t" \
      "v_fmac_f32 %4, %4, %16 "  CTRL "\n\t" \
      "v_fmac_f32 %5, %5, %16 "  CTRL "\n\t" \
      "v_fmac_f32 %6, %6, %16 "  CTRL "\n\t" \
      "v_fmac_f32 %7, %7, %16 "  CTRL "\n\t" \
      "v_fmac_f32 %8, %8, %16 "  CTRL "\n\t" \
      "v_fmac_f32 %9, %9, %16 "  CTRL "\n\t" \
      "v_fmac_f32 %10, %10, %16 " CTRL "\n\t" \
      "v_fmac_f32 %11, %11, %16 " CTRL "\n\t" \
      "v_fmac_f32 %12, %12, %16 " CTRL "\n\t" \
      "v_fmac_f32 %13, %13, %16 " CTRL "\n\t" \
      "v_fmac_f32 %14, %14, %16 " CTRL "\n\t" \
      "v_fmac_f32 %15, %15, %16 " CTRL \
      : "+v"(sr[0]),"+v"(sr[1]),"+v"(sr[2]),"+v"(sr[3]), \
        "+v"(sr[4]),"+v"(sr[5]),"+v"(sr[6]),"+v"(sr[7]), \
        "+v"(si[0]),"+v"(si[1]),"+v"(si[2]),"+v"(si[3]), \
        "+v"(si[4]),"+v"(si[5]),"+v"(si[6]),"+v"(si[7]) \
      : "v"(C))

#define DPP16_HI(CTRL, C, sr, si) \
  asm("s_nop 1\n\t" \
      "v_fmac_f32 %0, %0, %16 "  CTRL "\n\t" \
      "v_fmac_f32 %1, %1, %16 "  CTRL "\n\t" \
      "v_fmac_f32 %2, %2, %16 "  CTRL "\n\t" \
      "v_fmac_f32 %3, %3, %16 "  CTRL "\n\t" \
      "v_fmac_f32 %4, %4, %16 "  CTRL "\n\t" \
      "v_fmac_f32 %5, %5, %16 "  CTRL "\n\t" \
      "v_fmac_f32 %6, %6, %16 "  CTRL "\n\t" \
      "v_fmac_f32 %7, %7, %16 "  CTRL "\n\t" \
      "v_fmac_f32 %8, %8, %16 "  CTRL "\n\t" \
      "v_fmac_f32 %9, %9, %16 "  CTRL "\n\t" \
      "v_fmac_f32 %10, %10, %16 " CTRL "\n\t" \
      "v_fmac_f32 %11, %11, %16 " CTRL "\n\t" \
      "v_fmac_f32 %12, %12, %16 " CTRL "\n\t" \
      "v_fmac_f32 %13, %13, %16 " CTRL "\n\t" \
      "v_fmac_f32 %14, %14, %16 " CTRL "\n\t" \
      "v_fmac_f32 %15, %15, %16 " CTRL \
      : "+v"(sr[8]),"+v"(sr[9]),"+v"(sr[10]),"+v"(sr[11]), \
        "+v"(sr[12]),"+v"(sr[13]),"+v"(sr[14]),"+v"(sr[15]), \
        "+v"(si[8]),"+v"(si[9]),"+v"(si[10]),"+v"(si[11]), \
        "+v"(si[12]),"+v"(si[13]),"+v"(si[14]),"+v"(si[15]) \
      : "v"(C))

#define CTRL_QP1  "quad_perm:[1,0,3,2] row_mask:0xf bank_mask:0xf"   // lane^1
#define CTRL_QP2  "quad_perm:[2,3,0,1] row_mask:0xf bank_mask:0xf"   // lane^2
#define CTRL_ROR8 "row_ror:8 row_mask:0xf bank_mask:0xf"             // lane^8

// ---- permlane pair-trick shear (validated rounds 4-6 orientation) ----
template<int M>
__device__ __forceinline__ void pair_shear(float& a, float& b, float t) {
    if constexpr (M == 32) {
        auto p = __builtin_amdgcn_permlane32_swap(f2u(a), f2u(b), false, false);
        const float A = u2f(p[0]), B = u2f(p[1]);
        const float C = fmaf(-t, B, A);
        const float D = fmaf( t, A, B);
        auto q = __builtin_amdgcn_permlane32_swap(f2u(C), f2u(D), false, false);
        a = u2f(q[0]); b = u2f(q[1]);
    } else {
        auto p = __builtin_amdgcn_permlane16_swap(f2u(a), f2u(b), false, false);
        const float A = u2f(p[0]), B = u2f(p[1]);
        const float C = fmaf(-t, B, A);
        const float D = fmaf( t, A, B);
        auto q = __builtin_amdgcn_permlane16_swap(f2u(C), f2u(D), false, false);
        a = u2f(q[0]); b = u2f(q[1]);
    }
}

// ---- local shear on r-bit B; NB = compile-time neighbor-sign mask (mod layers)
template<int B, int NB>
__device__ __forceinline__ void local_ry(float (&sr)[16], float (&si)[16], float t) {
#pragma unroll
    for (int r0 = 0; r0 < 16; ++r0) {
        if ((r0 & (1 << B)) == 0) {
            const int r1 = r0 | (1 << B);
            const float tt = (__builtin_popcount(r0 & NB) & 1) ? -t : t;
            const float a0 = sr[r0], a1 = sr[r1];
            sr[r0] = fmaf(-tt, a1, a0);
            sr[r1] = fmaf( tt, a0, a1);
            const float b0 = si[r0], b1 = si[r1];
            si[r0] = fmaf(-tt, b1, b0);
            si[r1] = fmaf( tt, b0, b1);
        }
    }
}

struct Sig { float g16, g53, g42, g31, g20, g1, g0; };

// One RY layer; MOD => CZ-conjugated (t sign-modulated by neighbor bits).
template<bool MOD>
__device__ __forceinline__ void ry_layer(float (&sr)[16], float (&si)[16],
                                         float tp, int base, int lane, const Sig& sg) {
    {   // wire 0: amp bit 9 (lane bit 5), permlane32 pair
        float t = rdlane(tp, base + 0);
        if constexpr (MOD) t *= sg.g16;
#pragma unroll
        for (int r = 0; r < 16; r += 2) {
            pair_shear<32>(sr[r], sr[r+1], t);
            pair_shear<32>(si[r], si[r+1], t);
        }
    }
    {   // wire 1: amp bit 8 (lane bit 4), permlane16 pair
        float t = rdlane(tp, base + 1);
        if constexpr (MOD) t *= sg.g53;
#pragma unroll
        for (int r = 0; r < 16; r += 2) {
            pair_shear<16>(sr[r], sr[r+1], t);
            pair_shear<16>(si[r], si[r+1], t);
        }
    }
    {   // wire 2: lane mask 8, fused fmac+DPP row_ror:8
        float t = rdlane(tp, base + 2);
        if constexpr (MOD) t *= sg.g42;
        const float ts = (lane & 8) ? t : -t;
        DPP16_LO(CTRL_ROR8, ts, sr, si);
        DPP16_HI(CTRL_ROR8, ts, sr, si);
    }
    {   // wire 3: lane mask 4, DS pipe
        float t = rdlane(tp, base + 3);
        if constexpr (MOD) t *= sg.g31;
        const float ts = (lane & 4) ? t : -t;
#pragma unroll
        for (int r = 0; r < 16; ++r) {
            const float pr = __shfl_xor(sr[r], 4, 64);
            const float pi = __shfl_xor(si[r], 4, 64);
            sr[r] = fmaf(ts, pr, sr[r]);
            si[r] = fmaf(ts, pi, si[r]);
        }
    }
    {   // wire 4: lane mask 2, fused fmac+DPP quad_perm
        float t = rdlane(tp, base + 4);
        if constexpr (MOD) t *= sg.g20;
        const float ts = (lane & 2) ? t : -t;
        DPP16_LO(CTRL_QP2, ts, sr, si);
        DPP16_HI(CTRL_QP2, ts, sr, si);
    }
    {   // wire 5: lane mask 1, fused fmac+DPP; MOD also flips by r-bit3 (hi half)
        float t = rdlane(tp, base + 5);
        if constexpr (MOD) t *= sg.g1;
        const float ts = (lane & 1) ? t : -t;
        const float th = MOD ? -ts : ts;
        DPP16_LO(CTRL_QP1, ts, sr, si);
        DPP16_HI(CTRL_QP1, th, sr, si);
    }
    {   // wire 6: r bit 3; MOD: lane-bit0 sign + r-bit2 sign
        float t = rdlane(tp, base + 6);
        if constexpr (MOD) t *= sg.g0;
        local_ry<3, MOD ? 0x4 : 0>(sr, si, t);
    }
    local_ry<2, MOD ? 0xA : 0>(sr, si, rdlane(tp, base + 7));   // wire 7
    local_ry<1, MOD ? 0x5 : 0>(sr, si, rdlane(tp, base + 8));   // wire 8
    local_ry<0, MOD ? 0x2 : 0>(sr, si, rdlane(tp, base + 9));   // wire 9
}

__global__ void __launch_bounds__(256) qnn_kernel(
    const float* __restrict__ x,       // (B, 10)
    const float* __restrict__ params,  // (6, 10)
    const float* __restrict__ w_cls,   // (16, 10)
    const float* __restrict__ b_cls,   // (16,)
    float* __restrict__ out,           // (B, 16)
    int batch)
{
    const int lane = threadIdx.x & 63;
    const int wid  = threadIdx.x >> 6;
    const int b    = blockIdx.x * (blockDim.x >> 6) + wid;
    if (b >= batch) return;

    // ---- encoding angles ----
    float cx, sx;
    { const int l = (lane < NQ) ? lane : 0; __sincosf(x[b * NQ + l] * 0.5f, &sx, &cx); }

    // ---- RY params: tan-shear coeffs + deferred cos product ----
    float cp, sp;
    { const int l = (lane < 60) ? lane : 0; __sincosf(params[l] * 0.5f, &sp, &cp); }
    const float tp  = sp / cp;
    const float cpv = (lane < 60) ? cp : 1.f;
    float Cw = cpv;
#pragma unroll
    for (int k = 0; k < 6; ++k) Cw *= __shfl_xor(Cw, 1 << k, 64);
    const float C2 = Cw * Cw;

    // ---- neighbor-sign factors for CZ-conjugated layers ----
    Sig sg;
    sg.g16 = (lane & 16) ? -1.f : 1.f;                           // w0: lane bit4
    sg.g53 = (((lane >> 5) ^ (lane >> 3)) & 1) ? -1.f : 1.f;     // w1: bits 5,3
    sg.g42 = (((lane >> 4) ^ (lane >> 2)) & 1) ? -1.f : 1.f;     // w2: bits 4,2
    sg.g31 = (((lane >> 3) ^ (lane >> 1)) & 1) ? -1.f : 1.f;     // w3: bits 3,1
    sg.g20 = (((lane >> 2) ^ lane) & 1) ? -1.f : 1.f;            // w4: bits 2,0
    sg.g1  = (lane & 2) ? -1.f : 1.f;                            // w5: lane bit1
    sg.g0  = (lane & 1) ? -1.f : 1.f;                            // w6: lane bit0

    // ---- product state with the absorbed initial CZ-sign C|enc> ----
    float F = 1.f;
#pragma unroll
    for (int q = 0; q < 6; ++q) {
        const float cq = rdlane(cx, q), sq = rdlane(sx, q);
        F *= ((lane >> (5 - q)) & 1) ? sq : cq;
    }
    const int lpar = __popc(lane & (lane >> 1) & 0x1F) & 1;      // lane-pair parity
    F = u2f(f2u(F) ^ (u32(lpar) << 31));
    const float c6 = rdlane(cx, 6), s6r = rdlane(sx, 6);
    const float c7 = rdlane(cx, 7), s7  = rdlane(sx, 7);
    const float c8 = rdlane(cx, 8), s8  = rdlane(sx, 8);
    const float c9 = rdlane(cx, 9), s9  = rdlane(sx, 9);
    const float s6m = (lane & 1) ? -s6r : s6r;                   // boundary pair fold
    const float mm[4] = {c8 * c9, c8 * s9, s8 * c9, s8 * s9};
    const float nn[4] = {F * (c6 * c7), F * (c6 * s7), F * (s6m * c7), F * (s6m * s7)};
    const int kl = __popc(lane) & 3;
    const float pa = (kl == 0) ? 1.f : ((kl == 2) ? -1.f : 0.f);
    const float pb = (kl == 1) ? -1.f : ((kl == 3) ? 1.f : 0.f);
    const float phx[4] = {pa, pb, -pa, -pb};
    const float phy[4] = {pb, -pa, -pb, pa};

    float sr[16], si[16];
#pragma unroll
    for (int r = 0; r < 16; ++r) {
        const float Ar = nn[r >> 2] * mm[r & 3];
        const int j = ((__popc(r) & 3) + 2 * (__popc(r & (r >> 1) & 7) & 1)) & 3;
        sr[r] = Ar * phx[j];
        si[r] = Ar * phy[j];
    }

    // ---- layers: R1' R2 R3' R4 R5' R6 (MOD at d=0,2,4; no sign passes) ----
    ry_layer<true >(sr, si, tp,  0, lane, sg);
    ry_layer<false>(sr, si, tp, 10, lane, sg);
    ry_layer<true >(sr, si, tp, 20, lane, sg);
    ry_layer<false>(sr, si, tp, 30, lane, sg);
    ry_layer<true >(sr, si, tp, 40, lane, sg);
    ry_layer<false>(sr, si, tp, 50, lane, sg);

    // ---- probabilities + shared in-register tree (r-wire expvals + pt) ----
    float pp[16];
#pragma unroll
    for (int r = 0; r < 16; ++r) pp[r] = fmaf(sr[r], sr[r], si[r] * si[r]);

    float a4[8]; float f9 = 0.f;
#pragma unroll
    for (int i = 0; i < 8; ++i) { a4[i] = pp[2*i] + pp[2*i+1]; f9 += pp[2*i] - pp[2*i+1]; }
    float b4[4]; float f8 = 0.f;
#pragma unroll
    for (int i = 0; i < 4; ++i) { b4[i] = a4[2*i] + a4[2*i+1]; f8 += a4[2*i] - a4[2*i+1]; }
    const float cc0 = b4[0] + b4[1], cc1 = b4[2] + b4[3];
    float f7 = (b4[0] - b4[1]) + (b4[2] - b4[3]);
    float f6 = cc0 - cc1;
    const float pt = cc0 + cc1;

    // full-wave sums for the r-wire expvals (DS pipe)
#pragma unroll
    for (int k = 0; k < 6; ++k) {
        const int m = 1 << k;
        f6 += __shfl_xor(f6, m, 64);
        f7 += __shfl_xor(f7, m, 64);
        f8 += __shfl_xor(f8, m, 64);
        f9 += __shfl_xor(f9, m, 64);
    }

    // one WHT butterfly on pt: lane s ends with sum_l (-1)^{popc(l&s)} pt_l
    float v = pt;
#pragma unroll
    for (int k = 0; k < 6; ++k) {
        const int m = 1 << k;
        const float p = __shfl_xor(v, m, 64);
        const u32 xw = (lane & m) ? 0x80000000u : 0u;
        v = p + u2f(f2u(v) ^ xw);
    }
    const float e0 = rdlane(v, 32), e1 = rdlane(v, 16), e2 = rdlane(v, 8);
    const float e3 = rdlane(v, 4),  e4 = rdlane(v, 2),  e5 = rdlane(v, 1);

    // ---- linear head: lane k emits class k; C2 applied once ----
    if (lane < NCLS) {
        const float* wr = w_cls + lane * NQ;
        float dot = e0 * wr[0];
        dot = fmaf(e1, wr[1], dot);
        dot = fmaf(e2, wr[2], dot);
        dot = fmaf(e3, wr[3], dot);
        dot = fmaf(e4, wr[4], dot);
        dot = fmaf(e5, wr[5], dot);
        dot = fmaf(f6, wr[6], dot);
        dot = fmaf(f7, wr[7], dot);
        dot = fmaf(f8, wr[8], dot);
        dot = fmaf(f9, wr[9], dot);
        out[b * NCLS + lane] = fmaf(C2, dot, b_cls[lane]);
    }
}

extern "C" void kernel_launch(void* const* d_in, const int* in_sizes, int n_in,
                              void* d_out, int out_size, void* d_ws, size_t ws_size,
                              hipStream_t stream) {
    const float* x      = (const float*)d_in[0];
    const float* params = (const float*)d_in[1];
    const float* w_cls  = (const float*)d_in[2];
    const float* b_cls  = (const float*)d_in[3];
    float* out = (float*)d_out;

    const int batch = in_sizes[0] / NQ;            // 65536
    const int WAVES_PER_BLOCK = 4;                 // 256 threads
    dim3 block(64 * WAVES_PER_BLOCK);
    dim3 grid((batch + WAVES_PER_BLOCK - 1) / WAVES_PER_BLOCK);
    hipLaunchKernelGGL(qnn_kernel, grid, block, 0, stream, x, params, w_cls, b_cls, out, batch);
}